// Round 13
// baseline (251.490 us; speedup 1.0000x reference)
//
#include <hip/hip_runtime.h>
#include <math.h>

#define NN 50000
#define NE 800000
#define DIM 128
#define NH 8
#define HD 16
#define NTILE 3125            // NN/16 exactly
#define TPB 782               // ceil(NTILE/4) tile-groups per matrix
#define QVROW 256             // interleaved qv row: 256 shorts = 512 B
#define SCAN_B 196            // ceil(NN/256)

typedef short v8s __attribute__((ext_vector_type(8)));
typedef float v4f __attribute__((ext_vector_type(4)));

__device__ __forceinline__ unsigned short f2b(float f) {
    unsigned u = __float_as_uint(f);
    u = (u + 0x7fffu + ((u >> 16) & 1u)) >> 16;   // round-to-nearest-even
    return (unsigned short)u;
}
__device__ __forceinline__ float blo(unsigned w) { return __uint_as_float(w << 16); }
__device__ __forceinline__ float bhi(unsigned w) { return __uint_as_float(w & 0xffff0000u); }

// immediate-pattern lane swizzle (BitMode): src = ((lane & and) | or) ^ xor, per 32-half
template<int PAT>
__device__ __forceinline__ float swz(float x) {
    return __int_as_float(__builtin_amdgcn_ds_swizzle(__float_as_int(x), PAT));
}

// ---- K0: convert W{q,k,v,o} -> bf16 packed; zero cnt ----
#define NW4 (4 * DIM * DIM / 4)     // 16384 float4 of W
#define NC4 ((NN + 3) / 4)          // 12500 int4 of cnt
__global__ __launch_bounds__(256) void convert_kernel(
    const float* __restrict__ Wq, const float* __restrict__ Wk,
    const float* __restrict__ Wv, const float* __restrict__ Wo,
    unsigned short* __restrict__ Wb, int* __restrict__ cnt)
{
    int i = blockIdx.x * 256 + threadIdx.x;
    if (i < NW4) {
        int mat = i >> 12;            // 4096 float4 per matrix
        int off = i & 4095;
        const float* Wsrc = (mat == 0) ? Wq : (mat == 1) ? Wk : (mat == 2) ? Wv : Wo;
        float4 f = ((const float4*)Wsrc)[off];
        uint2 o;
        o.x = (unsigned)f2b(f.x) | ((unsigned)f2b(f.y) << 16);
        o.y = (unsigned)f2b(f.z) | ((unsigned)f2b(f.w) << 16);
        ((uint2*)(Wb + (size_t)mat * DIM * DIM))[off] = o;
    } else if (i < NW4 + NC4) {
        ((int4*)cnt)[i - NW4] = make_int4(0, 0, 0, 0);
    }
}

// ---- K1: QKV via MFMA + folded RANK histogram. One matrix per block.
// NO LDS (r12 post-mortem: 34.8KB staging capped occupancy at 4 blocks/CU
// =50% while W is 32KB and L2-hot across 782 blocks -- staging earns
// nothing). B fragments read directly from global W: per (nt,kt) a wave
// touches 16 rows x 64 contiguous bytes = full cachelines from L2.
// Occupancy cap moves to VGPR (~8 waves/SIMD); __syncthreads gone.
// The histogram's atomicAdd RETURN VALUE is the edge's rank within its
// target group; fill is atomic-free. ----
__global__ __launch_bounds__(256) void qkv_mfma_kernel(
    const float* __restrict__ x, const unsigned short* __restrict__ Wb,
    const float* __restrict__ bq, const float* __restrict__ bk, const float* __restrict__ bv,
    unsigned short* __restrict__ qvb, unsigned short* __restrict__ kb,
    const int* __restrict__ tgt, int* __restrict__ cnt, int* __restrict__ rank)
{
    const int mat = blockIdx.x / TPB;           // 0=q, 1=k, 2=v
    const int tg  = blockIdx.x % TPB;
    const int tid = threadIdx.x;
    const int lane = tid & 63;
    const int warp = tid >> 6;
    const int m = lane & 15;
    const int quad = lane >> 4;

    // folded rank-histogram: grid-stride over edges; store the returned
    // old count = per-target rank (coalesced 4B write)
    const int gsize = 3 * TPB * 256;
    for (int e = blockIdx.x * 256 + tid; e < NE; e += gsize)
        rank[e] = atomicAdd(cnt + tgt[e], 1);

    const int rt = tg * 4 + warp;
    if (rt >= NTILE) return;
    const int r0 = rt * 16;

    const unsigned short* Wg = Wb + (size_t)mat * DIM * DIM;
    const float* bias_p = (mat == 0) ? bq : (mat == 1) ? bk : bv;

    v8s a[4];
#pragma unroll
    for (int kt = 0; kt < 4; ++kt) {
        const float4* xr = (const float4*)(x + (size_t)(r0 + m) * DIM + kt * 32 + quad * 8);
        float4 f0 = xr[0], f1 = xr[1];
        v8s t;
        t[0] = (short)f2b(f0.x); t[1] = (short)f2b(f0.y);
        t[2] = (short)f2b(f0.z); t[3] = (short)f2b(f0.w);
        t[4] = (short)f2b(f1.x); t[5] = (short)f2b(f1.y);
        t[6] = (short)f2b(f1.z); t[7] = (short)f2b(f1.w);
        a[kt] = t;
    }

    const int i0 = (lane & 1) ? 2 : 0;        // which two rows this lane stores

#pragma unroll
    for (int nt = 0; nt < 8; ++nt) {
        v4f c = {0.f, 0.f, 0.f, 0.f};
#pragma unroll
        for (int kt = 0; kt < 4; ++kt) {
            v8s b = *(const v8s*)(Wg + (size_t)(nt * 16 + m) * DIM + kt * 32 + quad * 8);
            c = __builtin_amdgcn_mfma_f32_16x16x32_bf16(a[kt], b, c, 0, 0, 0);
        }
        int col = nt * 16 + m;           // C/D: col = lane&15
        float bias = bias_p[col];
        // pack (col, col^1) bf16 pair via partner-lane swizzle; keep the two
        // rows this lane is responsible for (even: i=0,1; odd: i=2,3)
        unsigned w0 = 0, w1 = 0;
#pragma unroll
        for (int i = 0; i < 4; ++i) {
            unsigned own  = (unsigned)f2b(c[i] + bias);
            unsigned part = (unsigned)__builtin_amdgcn_ds_swizzle((int)own, 0x041F) & 0xffffu;
            unsigned w = (lane & 1) ? (part | (own << 16)) : (own | (part << 16));
            if (i == i0)     w0 = w;
            if (i == i0 + 1) w1 = w;
        }
        int colb = nt * 16 + (m & ~1);   // pair-base col (dword-aligned)
        int rowa = r0 + quad * 4 + i0;
        if (mat == 1) {
            *(unsigned*)(kb + (size_t)rowa * DIM + colb)       = w0;
            *(unsigned*)(kb + (size_t)(rowa + 1) * DIM + colb) = w1;
        } else {
            int pos = colb * 2 + ((mat == 2) ? 2 : 0);   // interleaved qv layout
            *(unsigned*)(qvb + (size_t)rowa * QVROW + pos)       = w0;
            *(unsigned*)(qvb + (size_t)(rowa + 1) * QVROW + pos) = w1;
        }
    }
}

// ---- K2: per-block (256-elem) local exclusive scan + block sums ----
__global__ __launch_bounds__(256) void scan1_kernel(
    const int* __restrict__ cnt, int* __restrict__ off, int* __restrict__ bsum)
{
    __shared__ int ws4[4];
    const int tid = threadIdx.x, lane = tid & 63, wid = tid >> 6;
    int i = blockIdx.x * 256 + tid;
    int v0 = (i < NN) ? cnt[i] : 0;
    int incl = v0;
#pragma unroll
    for (int d = 1; d < 64; d <<= 1) {
        int t = __shfl_up(incl, d);
        if (lane >= d) incl += t;
    }
    if (lane == 63) ws4[wid] = incl;
    __syncthreads();
    int wexcl = 0;
#pragma unroll
    for (int t = 0; t < 3; ++t) if (t < wid) wexcl += ws4[t];
    if (i < NN) off[i] = wexcl + incl - v0;
    if (tid == 255) bsum[blockIdx.x] = wexcl + incl;
}

// ---- K3: each block scans all 196 block sums (redundantly), adds its own
// base to off; last block writes off[NN] = total. ----
__global__ __launch_bounds__(256) void scan23_kernel(
    const int* __restrict__ bsum, int* __restrict__ off)
{
    __shared__ int ws4[4];
    __shared__ int base_s, total_s;
    const int tid = threadIdx.x, lane = tid & 63, wid = tid >> 6;
    int v0 = (tid < SCAN_B) ? bsum[tid] : 0;
    int incl = v0;
#pragma unroll
    for (int d = 1; d < 64; d <<= 1) {
        int t = __shfl_up(incl, d);
        if (lane >= d) incl += t;
    }
    if (lane == 63) ws4[wid] = incl;
    __syncthreads();
    int wexcl = 0;
#pragma unroll
    for (int t = 0; t < 3; ++t) if (t < wid) wexcl += ws4[t];
    int excl = wexcl + incl - v0;
    if (tid == blockIdx.x) base_s = excl;
    if (tid == SCAN_B - 1) total_s = excl + v0;
    __syncthreads();
    int i = blockIdx.x * 256 + tid;
    if (i < NN) off[i] += base_s;
    if (blockIdx.x == SCAN_B - 1 && tid == 0) off[NN] = total_s;
}

// ---- K4: fill CSR, ATOMIC-FREE: pos = off[tgt] + rank. ----
__global__ __launch_bounds__(256) void fill_kernel(
    const int* __restrict__ tgt, const int* __restrict__ src,
    const int* __restrict__ off, const int* __restrict__ rank,
    int* __restrict__ edge_src)
{
    int e = blockIdx.x * 256 + threadIdx.x;
    if (e >= NE) return;
    int pos = off[tgt[e]] + rank[e];
    edge_src[pos] = src[e];
}

// ---- K5: fused attention (r11 version, at its gather-latency floor).
// 1 wave/node, interleaved-qv 8x8B gathers (MLP=8), SGPR gather
// addressing, swizzle xor-tree, VGPR 24. ----
__global__ __launch_bounds__(256) void attn_kernel(
    const int* __restrict__ off, const int* __restrict__ edge_src,
    const unsigned short* __restrict__ qvb, const unsigned short* __restrict__ kb,
    unsigned short* __restrict__ aggb)
{
    const int tid = threadIdx.x;
    const int lane = tid & 63;
    const int node = blockIdx.x * 4 + (tid >> 6);
    if (node >= NN) return;

    const int base = __builtin_amdgcn_readfirstlane(off[node]);
    const int deg  = __builtin_amdgcn_readfirstlane(off[node + 1]) - base;

    unsigned kw = *(const unsigned*)(kb + (size_t)node * DIM + 2 * lane);
    const float klo = blo(kw), khi = bhi(kw);
    const int j = lane & 7;             // position within 8-lane head group

    float ax = 0.f, ay = 0.f, ss = 0.f;

    uint2 qv[8];                        // literal-indexed only -> registers

    // one gather: uniform row base (SALU) + lane*8 offset
#define G1(BB, I) { \
        int si = __builtin_amdgcn_readlane(srcv, (BB) * 8 + (I)); \
        qv[I] = ((const uint2*)(qvb + ((size_t)(unsigned)si << 8)))[lane]; }

#define ACC1(I) { float pi = swz<((I) << 5) | 0x18>(p); \
        unsigned vv = qv[I].y; ax += pi * blo(vv); ay += pi * bhi(vv); }

    for (int c0 = 0; c0 < deg; c0 += 64) {
        const int nchunk = min(deg - c0, 64);                  // wave-uniform
        int srcv = edge_src[base + min(c0 + lane, deg - 1)];   // coalesced, all valid
        const int nbt = (nchunk + 7) >> 3;                     // 1..8 batches
        for (int bb = 0; bb < nbt; ++bb) {
            G1(bb, 0) G1(bb, 1) G1(bb, 2) G1(bb, 3)
            G1(bb, 4) G1(bb, 5) G1(bb, 6) G1(bb, 7)
            const int nbu = nchunk - bb * 8;                   // valid edges
            float part0 = blo(qv[0].x) * klo + bhi(qv[0].x) * khi;
            float part1 = blo(qv[1].x) * klo + bhi(qv[1].x) * khi;
            float part2 = blo(qv[2].x) * klo + bhi(qv[2].x) * khi;
            float part3 = blo(qv[3].x) * klo + bhi(qv[3].x) * khi;
            float part4 = blo(qv[4].x) * klo + bhi(qv[4].x) * khi;
            float part5 = blo(qv[5].x) * klo + bhi(qv[5].x) * khi;
            float part6 = blo(qv[6].x) * klo + bhi(qv[6].x) * khi;
            float part7 = blo(qv[7].x) * klo + bhi(qv[7].x) * khi;
            // xor-tree: stage 1 (xor 1), stage 2 (xor 2), stage 3 (xor 4)
            float r10 = ((j & 1) ? part1 : part0) + swz<0x041F>((j & 1) ? part0 : part1);
            float r11 = ((j & 1) ? part3 : part2) + swz<0x041F>((j & 1) ? part2 : part3);
            float r12 = ((j & 1) ? part5 : part4) + swz<0x041F>((j & 1) ? part4 : part5);
            float r13 = ((j & 1) ? part7 : part6) + swz<0x041F>((j & 1) ? part6 : part7);
            float r20 = ((j & 2) ? r11 : r10) + swz<0x081F>((j & 2) ? r10 : r11);
            float r21 = ((j & 2) ? r13 : r12) + swz<0x081F>((j & 2) ? r12 : r13);
            float tot = ((j & 4) ? r21 : r20) + swz<0x101F>((j & 4) ? r20 : r21);
            float p = (j < nbu) ? __expf(tot * 0.25f) : 0.f;   // 1/sqrt(HD); tail->0
            ss += p;                                           // own edge only
            ACC1(0) ACC1(1) ACC1(2) ACC1(3)
            ACC1(4) ACC1(5) ACC1(6) ACC1(7)
        }
    }
#undef G1
#undef ACC1

    // reduce ss across the 8-lane head group
    ss += swz<0x041F>(ss);
    ss += swz<0x081F>(ss);
    ss += swz<0x101F>(ss);

    unsigned* ap = (unsigned*)(aggb + (size_t)node * DIM + 2 * lane);
    if (deg == 0) {
        *ap = 0u;
    } else {
        float inv = 1.f / ss;
        *ap = (unsigned)f2b(ax * inv) | ((unsigned)f2b(ay * inv) << 16);
    }
}

// ---- K6: out = agg @ Wo.T + bo via MFMA. NO LDS (same rationale as K1:
// Wo is 32KB, L2-hot across 782 blocks; LDS staging only capped occupancy). ----
__global__ __launch_bounds__(256) void outproj_mfma_kernel(
    const unsigned short* __restrict__ aggb, const unsigned short* __restrict__ Wob,
    const float* __restrict__ bo, float* __restrict__ out)
{
    const int tid = threadIdx.x;
    const int lane = tid & 63;
    const int warp = tid >> 6;
    const int m = lane & 15;
    const int quad = lane >> 4;

    const int rt = blockIdx.x * 4 + warp;
    if (rt >= NTILE) return;
    const int r0 = rt * 16;

    v8s a[4];
#pragma unroll
    for (int kt = 0; kt < 4; ++kt)
        a[kt] = *(const v8s*)(aggb + (size_t)(r0 + m) * DIM + kt * 32 + quad * 8);

#pragma unroll
    for (int nt = 0; nt < 8; ++nt) {
        v4f c = {0.f, 0.f, 0.f, 0.f};
#pragma unroll
        for (int kt = 0; kt < 4; ++kt) {
            v8s b = *(const v8s*)(Wob + (size_t)(nt * 16 + m) * DIM + kt * 32 + quad * 8);
            c = __builtin_amdgcn_mfma_f32_16x16x32_bf16(a[kt], b, c, 0, 0, 0);
        }
        int col = nt * 16 + m;
        float bias = bo[col];
#pragma unroll
        for (int i = 0; i < 4; ++i) {
            int row = r0 + quad * 4 + i;
            out[(size_t)row * DIM + col] = c[i] + bias;
        }
    }
}

extern "C" void kernel_launch(void* const* d_in, const int* in_sizes, int n_in,
                              void* d_out, int out_size, void* d_ws, size_t ws_size,
                              hipStream_t stream) {
    const float* x  = (const float*)d_in[0];
    const int*   ei = (const int*)d_in[1];      // [2, NE]: row0 = tgt, row1 = src
    const float* Wq = (const float*)d_in[2];
    const float* bq = (const float*)d_in[3];
    const float* Wk = (const float*)d_in[4];
    const float* bk = (const float*)d_in[5];
    const float* Wv = (const float*)d_in[6];
    const float* bv = (const float*)d_in[7];
    const float* Wo = (const float*)d_in[8];
    const float* bo = (const float*)d_in[9];

    const int* tgt = ei;
    const int* src = ei + NE;

    char* ws = (char*)d_ws;
    const size_t SZ_QV = (size_t)NN * QVROW * 2;    // 25.6 MB interleaved q+v
    const size_t SZ_BF = (size_t)NN * DIM * 2;      // 12.8 MB

    unsigned short* qvb  = (unsigned short*)(ws);
    unsigned short* kb   = (unsigned short*)(ws + SZ_QV);
    unsigned short* aggb = (unsigned short*)(ws + SZ_QV + SZ_BF);
    unsigned short* Wb   = (unsigned short*)(ws + SZ_QV + 2 * SZ_BF);  // 4 mats, 128 KB

    char* wi = ws + SZ_QV + 2 * SZ_BF + (size_t)4 * DIM * DIM * 2;
    int* cnt      = (int*)(wi);
    int* off      = (int*)(wi + (size_t)NN * 4);
    int* rank     = (int*)(wi + (size_t)(2 * NN + 1) * 4);
    int* edge_src = (int*)(wi + (size_t)(2 * NN + 1 + NE) * 4);
    int* bsum     = (int*)(wi + (size_t)(2 * NN + 1 + 2 * NE) * 4);

    const int conv_blocks = (NW4 + NC4 + 255) / 256;
    const int edge_blocks = (NE + 255) / 256;  // 3125

    convert_kernel<<<conv_blocks, 256, 0, stream>>>(Wq, Wk, Wv, Wo, Wb, cnt);
    qkv_mfma_kernel<<<3 * TPB, 256, 0, stream>>>(x, Wb, bq, bk, bv, qvb, kb, tgt, cnt, rank);
    scan1_kernel<<<SCAN_B, 256, 0, stream>>>(cnt, off, bsum);
    scan23_kernel<<<SCAN_B, 256, 0, stream>>>(bsum, off);
    fill_kernel<<<edge_blocks, 256, 0, stream>>>(tgt, src, off, rank, edge_src);
    attn_kernel<<<(NN + 3) / 4, 256, 0, stream>>>(off, edge_src, qvb, kb, aggb);
    outproj_mfma_kernel<<<TPB, 256, 0, stream>>>(
        aggb, Wb + (size_t)3 * DIM * DIM, bo, (float*)d_out);
}

// Round 15
// 220.905 us; speedup vs baseline: 1.1385x; 1.1385x over previous
//
#include <hip/hip_runtime.h>
#include <math.h>

#define NN 50000
#define NE 800000
#define DIM 128
#define NH 8
#define HD 16
#define NTILE 3125            // NN/16 exactly
#define TPB 782               // ceil(NTILE/4) tile-groups per matrix
#define LROW 136              // LDS row stride in shorts (128 + 8 pad)
#define QVROW 256             // interleaved qv row: 256 shorts = 512 B
#define SCAN_B 196            // ceil(NN/256)
#define GSIZE (3 * TPB * 256) // qkv histogram grid-stride = 600576

typedef short v8s __attribute__((ext_vector_type(8)));
typedef float v4f __attribute__((ext_vector_type(4)));

__device__ __forceinline__ unsigned short f2b(float f) {
    unsigned u = __float_as_uint(f);
    u = (u + 0x7fffu + ((u >> 16) & 1u)) >> 16;   // round-to-nearest-even
    return (unsigned short)u;
}
__device__ __forceinline__ float blo(unsigned w) { return __uint_as_float(w << 16); }
__device__ __forceinline__ float bhi(unsigned w) { return __uint_as_float(w & 0xffff0000u); }

// immediate-pattern lane swizzle (BitMode): src = ((lane & and) | or) ^ xor, per 32-half
template<int PAT>
__device__ __forceinline__ float swz(float x) {
    return __int_as_float(__builtin_amdgcn_ds_swizzle(__float_as_int(x), PAT));
}

// ---- K0: convert W{q,k,v,o} -> bf16 packed; zero cnt[4][NN] ----
#define NW4 (4 * DIM * DIM / 4)     // 16384 float4 of W
#define NC4 (NN)                    // 4*NN ints = NN int4
__global__ __launch_bounds__(256) void convert_kernel(
    const float* __restrict__ Wq, const float* __restrict__ Wk,
    const float* __restrict__ Wv, const float* __restrict__ Wo,
    unsigned short* __restrict__ Wb, int* __restrict__ cnt)
{
    int i = blockIdx.x * 256 + threadIdx.x;
    if (i < NW4) {
        int mat = i >> 12;            // 4096 float4 per matrix
        int off = i & 4095;
        const float* Wsrc = (mat == 0) ? Wq : (mat == 1) ? Wk : (mat == 2) ? Wv : Wo;
        float4 f = ((const float4*)Wsrc)[off];
        uint2 o;
        o.x = (unsigned)f2b(f.x) | ((unsigned)f2b(f.y) << 16);
        o.y = (unsigned)f2b(f.z) | ((unsigned)f2b(f.w) << 16);
        ((uint2*)(Wb + (size_t)mat * DIM * DIM))[off] = o;
    } else if (i < NW4 + NC4) {
        ((int4*)cnt)[i - NW4] = make_int4(0, 0, 0, 0);
    }
}

// ---- K1: QKV via MFMA (r12 LDS version — r13 proved global-direct B reads
// put an L2-hit in every MFMA chain, +21us) + folded RANK histogram with
// 4-WAY COUNTER SPLIT: copy = blockIdx.x & 3 (wave-uniform). Per-address
// atomic chain 16 -> 4, 4x more L2 lines -> line-serialized atomic stream
// (the ~55us floor, r11 fill / r12 qkv evidence) drops ~3-4x. Bucket order
// is permutation-invariant so fill just adds lower-copy prefixes. ----
__global__ __launch_bounds__(256) void qkv_mfma_kernel(
    const float* __restrict__ x, const unsigned short* __restrict__ Wb,
    const float* __restrict__ bq, const float* __restrict__ bk, const float* __restrict__ bv,
    unsigned short* __restrict__ qvb, unsigned short* __restrict__ kb,
    const int* __restrict__ tgt, int* __restrict__ cnt, int* __restrict__ rank)
{
    __shared__ unsigned short Wl[DIM * LROW];   // 34816 B
    const int mat = blockIdx.x / TPB;           // 0=q, 1=k, 2=v
    const int tg  = blockIdx.x % TPB;
    const int tid = threadIdx.x;
    const int lane = tid & 63;
    const int warp = tid >> 6;
    const int m = lane & 15;
    const int quad = lane >> 4;

    // folded rank-histogram into copy (blockIdx.x & 3)
    int* mycnt = cnt + (size_t)(blockIdx.x & 3) * NN;
    for (int e = blockIdx.x * 256 + tid; e < NE; e += GSIZE)
        rank[e] = atomicAdd(mycnt + tgt[e], 1);

    const unsigned short* Wg = Wb + (size_t)mat * DIM * DIM;
#pragma unroll
    for (int it = 0; it < 8; ++it) {
        int chunk = it * 256 + tid;           // 0..2047
        int row = chunk >> 4, c8 = chunk & 15;
        *(uint4*)(Wl + row * LROW + c8 * 8) = ((const uint4*)Wg)[chunk];
    }
    __syncthreads();

    const int rt = tg * 4 + warp;
    if (rt >= NTILE) return;
    const int r0 = rt * 16;

    const float* bias_p = (mat == 0) ? bq : (mat == 1) ? bk : bv;

    v8s a[4];
#pragma unroll
    for (int kt = 0; kt < 4; ++kt) {
        const float4* xr = (const float4*)(x + (size_t)(r0 + m) * DIM + kt * 32 + quad * 8);
        float4 f0 = xr[0], f1 = xr[1];
        v8s t;
        t[0] = (short)f2b(f0.x); t[1] = (short)f2b(f0.y);
        t[2] = (short)f2b(f0.z); t[3] = (short)f2b(f0.w);
        t[4] = (short)f2b(f1.x); t[5] = (short)f2b(f1.y);
        t[6] = (short)f2b(f1.z); t[7] = (short)f2b(f1.w);
        a[kt] = t;
    }

    const int i0 = (lane & 1) ? 2 : 0;        // which two rows this lane stores

#pragma unroll
    for (int nt = 0; nt < 8; ++nt) {
        v4f c = {0.f, 0.f, 0.f, 0.f};
#pragma unroll
        for (int kt = 0; kt < 4; ++kt) {
            v8s b = *(const v8s*)(Wl + (nt * 16 + m) * LROW + kt * 32 + quad * 8);
            c = __builtin_amdgcn_mfma_f32_16x16x32_bf16(a[kt], b, c, 0, 0, 0);
        }
        int col = nt * 16 + m;           // C/D: col = lane&15
        float bias = bias_p[col];
        // pack (col, col^1) bf16 pair via partner-lane swizzle; keep the two
        // rows this lane is responsible for (even: i=0,1; odd: i=2,3)
        unsigned w0 = 0, w1 = 0;
#pragma unroll
        for (int i = 0; i < 4; ++i) {
            unsigned own  = (unsigned)f2b(c[i] + bias);
            unsigned part = (unsigned)__builtin_amdgcn_ds_swizzle((int)own, 0x041F) & 0xffffu;
            unsigned w = (lane & 1) ? (part | (own << 16)) : (own | (part << 16));
            if (i == i0)     w0 = w;
            if (i == i0 + 1) w1 = w;
        }
        int colb = nt * 16 + (m & ~1);   // pair-base col (dword-aligned)
        int rowa = r0 + quad * 4 + i0;
        if (mat == 1) {
            *(unsigned*)(kb + (size_t)rowa * DIM + colb)       = w0;
            *(unsigned*)(kb + (size_t)(rowa + 1) * DIM + colb) = w1;
        } else {
            int pos = colb * 2 + ((mat == 2) ? 2 : 0);   // interleaved qv layout
            *(unsigned*)(qvb + (size_t)rowa * QVROW + pos)       = w0;
            *(unsigned*)(qvb + (size_t)(rowa + 1) * QVROW + pos) = w1;
        }
    }
}

// ---- K2: per-block (256-elem) local exclusive scan + block sums.
// Node count = sum of the 4 counter copies. ----
__global__ __launch_bounds__(256) void scan1_kernel(
    const int* __restrict__ cnt, int* __restrict__ off, int* __restrict__ bsum)
{
    __shared__ int ws4[4];
    const int tid = threadIdx.x, lane = tid & 63, wid = tid >> 6;
    int i = blockIdx.x * 256 + tid;
    int v0 = 0;
    if (i < NN)
        v0 = cnt[i] + cnt[NN + i] + cnt[2 * NN + i] + cnt[3 * NN + i];
    int incl = v0;
#pragma unroll
    for (int d = 1; d < 64; d <<= 1) {
        int t = __shfl_up(incl, d);
        if (lane >= d) incl += t;
    }
    if (lane == 63) ws4[wid] = incl;
    __syncthreads();
    int wexcl = 0;
#pragma unroll
    for (int t = 0; t < 3; ++t) if (t < wid) wexcl += ws4[t];
    if (i < NN) off[i] = wexcl + incl - v0;
    if (tid == 255) bsum[blockIdx.x] = wexcl + incl;
}

// ---- K3: each block scans all 196 block sums (redundantly), adds its own
// base to off; last block writes off[NN] = total. ----
__global__ __launch_bounds__(256) void scan23_kernel(
    const int* __restrict__ bsum, int* __restrict__ off)
{
    __shared__ int ws4[4];
    __shared__ int base_s, total_s;
    const int tid = threadIdx.x, lane = tid & 63, wid = tid >> 6;
    int v0 = (tid < SCAN_B) ? bsum[tid] : 0;
    int incl = v0;
#pragma unroll
    for (int d = 1; d < 64; d <<= 1) {
        int t = __shfl_up(incl, d);
        if (lane >= d) incl += t;
    }
    if (lane == 63) ws4[wid] = incl;
    __syncthreads();
    int wexcl = 0;
#pragma unroll
    for (int t = 0; t < 3; ++t) if (t < wid) wexcl += ws4[t];
    int excl = wexcl + incl - v0;
    if (tid == blockIdx.x) base_s = excl;
    if (tid == SCAN_B - 1) total_s = excl + v0;
    __syncthreads();
    int i = blockIdx.x * 256 + tid;
    if (i < NN) off[i] += base_s;
    if (blockIdx.x == SCAN_B - 1 && tid == 0) off[NN] = total_s;
}

// ---- K4: fill CSR, ATOMIC-FREE: pos = off[t] + prefix(copies < c) + rank.
// Copy index c = ((e mod GSIZE) >> 8) & 3 -- block-uniform in this grid
// (GSIZE is a multiple of 256), so no divergence; counter reads L2-hot. ----
__global__ __launch_bounds__(256) void fill_kernel(
    const int* __restrict__ tgt, const int* __restrict__ src,
    const int* __restrict__ off, const int* __restrict__ rank,
    const int* __restrict__ cnt, int* __restrict__ edge_src)
{
    int e = blockIdx.x * 256 + threadIdx.x;
    if (e >= NE) return;
    int t = tgt[e];
    int eb = (e >= GSIZE) ? e - GSIZE : e;
    int c = (eb >> 8) & 3;              // which counter copy ranked this edge
    int base = off[t];
    if (c > 0) base += cnt[t];
    if (c > 1) base += cnt[NN + t];
    if (c > 2) base += cnt[2 * NN + t];
    edge_src[base + rank[e]] = src[e];
}

// ---- K5: fused attention (r11 version, at its gather-latency floor).
// 1 wave/node, interleaved-qv 8x8B gathers (MLP=8), SGPR gather
// addressing, swizzle xor-tree, VGPR 24. ----
__global__ __launch_bounds__(256) void attn_kernel(
    const int* __restrict__ off, const int* __restrict__ edge_src,
    const unsigned short* __restrict__ qvb, const unsigned short* __restrict__ kb,
    unsigned short* __restrict__ aggb)
{
    const int tid = threadIdx.x;
    const int lane = tid & 63;
    const int node = blockIdx.x * 4 + (tid >> 6);
    if (node >= NN) return;

    const int base = __builtin_amdgcn_readfirstlane(off[node]);
    const int deg  = __builtin_amdgcn_readfirstlane(off[node + 1]) - base;

    unsigned kw = *(const unsigned*)(kb + (size_t)node * DIM + 2 * lane);
    const float klo = blo(kw), khi = bhi(kw);
    const int j = lane & 7;             // position within 8-lane head group

    float ax = 0.f, ay = 0.f, ss = 0.f;

    uint2 qv[8];                        // literal-indexed only -> registers

    // one gather: uniform row base (SALU) + lane*8 offset
#define G1(BB, I) { \
        int si = __builtin_amdgcn_readlane(srcv, (BB) * 8 + (I)); \
        qv[I] = ((const uint2*)(qvb + ((size_t)(unsigned)si << 8)))[lane]; }

#define ACC1(I) { float pi = swz<((I) << 5) | 0x18>(p); \
        unsigned vv = qv[I].y; ax += pi * blo(vv); ay += pi * bhi(vv); }

    for (int c0 = 0; c0 < deg; c0 += 64) {
        const int nchunk = min(deg - c0, 64);                  // wave-uniform
        int srcv = edge_src[base + min(c0 + lane, deg - 1)];   // coalesced, all valid
        const int nbt = (nchunk + 7) >> 3;                     // 1..8 batches
        for (int bb = 0; bb < nbt; ++bb) {
            G1(bb, 0) G1(bb, 1) G1(bb, 2) G1(bb, 3)
            G1(bb, 4) G1(bb, 5) G1(bb, 6) G1(bb, 7)
            const int nbu = nchunk - bb * 8;                   // valid edges
            float part0 = blo(qv[0].x) * klo + bhi(qv[0].x) * khi;
            float part1 = blo(qv[1].x) * klo + bhi(qv[1].x) * khi;
            float part2 = blo(qv[2].x) * klo + bhi(qv[2].x) * khi;
            float part3 = blo(qv[3].x) * klo + bhi(qv[3].x) * khi;
            float part4 = blo(qv[4].x) * klo + bhi(qv[4].x) * khi;
            float part5 = blo(qv[5].x) * klo + bhi(qv[5].x) * khi;
            float part6 = blo(qv[6].x) * klo + bhi(qv[6].x) * khi;
            float part7 = blo(qv[7].x) * klo + bhi(qv[7].x) * khi;
            // xor-tree: stage 1 (xor 1), stage 2 (xor 2), stage 3 (xor 4)
            float r10 = ((j & 1) ? part1 : part0) + swz<0x041F>((j & 1) ? part0 : part1);
            float r11 = ((j & 1) ? part3 : part2) + swz<0x041F>((j & 1) ? part2 : part3);
            float r12 = ((j & 1) ? part5 : part4) + swz<0x041F>((j & 1) ? part4 : part5);
            float r13 = ((j & 1) ? part7 : part6) + swz<0x041F>((j & 1) ? part6 : part7);
            float r20 = ((j & 2) ? r11 : r10) + swz<0x081F>((j & 2) ? r10 : r11);
            float r21 = ((j & 2) ? r13 : r12) + swz<0x081F>((j & 2) ? r12 : r13);
            float tot = ((j & 4) ? r21 : r20) + swz<0x101F>((j & 4) ? r20 : r21);
            float p = (j < nbu) ? __expf(tot * 0.25f) : 0.f;   // 1/sqrt(HD); tail->0
            ss += p;                                           // own edge only
            ACC1(0) ACC1(1) ACC1(2) ACC1(3)
            ACC1(4) ACC1(5) ACC1(6) ACC1(7)
        }
    }
#undef G1
#undef ACC1

    // reduce ss across the 8-lane head group
    ss += swz<0x041F>(ss);
    ss += swz<0x081F>(ss);
    ss += swz<0x101F>(ss);

    unsigned* ap = (unsigned*)(aggb + (size_t)node * DIM + 2 * lane);
    if (deg == 0) {
        *ap = 0u;
    } else {
        float inv = 1.f / ss;
        *ap = (unsigned)f2b(ax * inv) | ((unsigned)f2b(ay * inv) << 16);
    }
}

// ---- K6: out = agg @ Wo.T + bo via MFMA, Wo staged in LDS (r12 version;
// r13's no-LDS variant regressed), fp32 out ----
__global__ __launch_bounds__(256) void outproj_mfma_kernel(
    const unsigned short* __restrict__ aggb, const unsigned short* __restrict__ Wob,
    const float* __restrict__ bo, float* __restrict__ out)
{
    __shared__ unsigned short Wl[DIM * LROW];
    const int tid = threadIdx.x;
    const int lane = tid & 63;
    const int warp = tid >> 6;
    const int m = lane & 15;
    const int quad = lane >> 4;

#pragma unroll
    for (int it = 0; it < 8; ++it) {
        int chunk = it * 256 + tid;
        int row = chunk >> 4, c8 = chunk & 15;
        *(uint4*)(Wl + row * LROW + c8 * 8) = ((const uint4*)Wob)[chunk];
    }
    __syncthreads();

    const int rt = blockIdx.x * 4 + warp;
    if (rt >= NTILE) return;
    const int r0 = rt * 16;

    v8s a[4];
#pragma unroll
    for (int kt = 0; kt < 4; ++kt)
        a[kt] = *(const v8s*)(aggb + (size_t)(r0 + m) * DIM + kt * 32 + quad * 8);

#pragma unroll
    for (int nt = 0; nt < 8; ++nt) {
        v4f c = {0.f, 0.f, 0.f, 0.f};
#pragma unroll
        for (int kt = 0; kt < 4; ++kt) {
            v8s b = *(const v8s*)(Wl + (nt * 16 + m) * LROW + kt * 32 + quad * 8);
            c = __builtin_amdgcn_mfma_f32_16x16x32_bf16(a[kt], b, c, 0, 0, 0);
        }
        int col = nt * 16 + m;
        float bias = bo[col];
#pragma unroll
        for (int i = 0; i < 4; ++i) {
            int row = r0 + quad * 4 + i;
            out[(size_t)row * DIM + col] = c[i] + bias;
        }
    }
}

extern "C" void kernel_launch(void* const* d_in, const int* in_sizes, int n_in,
                              void* d_out, int out_size, void* d_ws, size_t ws_size,
                              hipStream_t stream) {
    const float* x  = (const float*)d_in[0];
    const int*   ei = (const int*)d_in[1];      // [2, NE]: row0 = tgt, row1 = src
    const float* Wq = (const float*)d_in[2];
    const float* bq = (const float*)d_in[3];
    const float* Wk = (const float*)d_in[4];
    const float* bk = (const float*)d_in[5];
    const float* Wv = (const float*)d_in[6];
    const float* bv = (const float*)d_in[7];
    const float* Wo = (const float*)d_in[8];
    const float* bo = (const float*)d_in[9];

    const int* tgt = ei;
    const int* src = ei + NE;

    char* ws = (char*)d_ws;
    const size_t SZ_QV = (size_t)NN * QVROW * 2;    // 25.6 MB interleaved q+v
    const size_t SZ_BF = (size_t)NN * DIM * 2;      // 12.8 MB

    unsigned short* qvb  = (unsigned short*)(ws);
    unsigned short* kb   = (unsigned short*)(ws + SZ_QV);
    unsigned short* aggb = (unsigned short*)(ws + SZ_QV + SZ_BF);
    unsigned short* Wb   = (unsigned short*)(ws + SZ_QV + 2 * SZ_BF);  // 4 mats, 128 KB

    char* wi = ws + SZ_QV + 2 * SZ_BF + (size_t)4 * DIM * DIM * 2;
    int* cnt      = (int*)(wi);                                   // [4][NN]
    int* off      = (int*)(wi + (size_t)4 * NN * 4);
    int* rank     = (int*)(wi + (size_t)(5 * NN + 1) * 4);
    int* edge_src = (int*)(wi + (size_t)(5 * NN + 1 + NE) * 4);
    int* bsum     = (int*)(wi + (size_t)(5 * NN + 1 + 2 * NE) * 4);

    const int conv_blocks = (NW4 + NC4 + 255) / 256;
    const int edge_blocks = (NE + 255) / 256;  // 3125

    convert_kernel<<<conv_blocks, 256, 0, stream>>>(Wq, Wk, Wv, Wo, Wb, cnt);
    qkv_mfma_kernel<<<3 * TPB, 256, 0, stream>>>(x, Wb, bq, bk, bv, qvb, kb, tgt, cnt, rank);
    scan1_kernel<<<SCAN_B, 256, 0, stream>>>(cnt, off, bsum);
    scan23_kernel<<<SCAN_B, 256, 0, stream>>>(bsum, off);
    fill_kernel<<<edge_blocks, 256, 0, stream>>>(tgt, src, off, rank, cnt, edge_src);
    attn_kernel<<<(NN + 3) / 4, 256, 0, stream>>>(off, edge_src, qvb, kb, aggb);
    outproj_mfma_kernel<<<TPB, 256, 0, stream>>>(
        aggb, Wb + (size_t)3 * DIM * DIM, bo, (float*)d_out);
}

// Round 17
// 219.639 us; speedup vs baseline: 1.1450x; 1.0058x over previous
//
#include <hip/hip_runtime.h>
#include <math.h>

#define NN 50000
#define NE 800000
#define DIM 128
#define NH 8
#define HD 16
#define NTILE 3125            // NN/16 exactly
#define TPB 782               // ceil(NTILE/4) tile-groups per matrix
#define LROW 136              // LDS row stride in shorts (128 + 8 pad)
#define QVROW 256             // interleaved qv row: 256 shorts = 512 B
#define SCAN_B 196            // ceil(NN/256)

typedef short v8s __attribute__((ext_vector_type(8)));
typedef float v4f __attribute__((ext_vector_type(4)));

__device__ __forceinline__ unsigned short f2b(float f) {
    unsigned u = __float_as_uint(f);
    u = (u + 0x7fffu + ((u >> 16) & 1u)) >> 16;   // round-to-nearest-even
    return (unsigned short)u;
}
__device__ __forceinline__ float blo(unsigned w) { return __uint_as_float(w << 16); }
__device__ __forceinline__ float bhi(unsigned w) { return __uint_as_float(w & 0xffff0000u); }

// immediate-pattern lane swizzle (BitMode): src = ((lane & and) | or) ^ xor, per 32-half
template<int PAT>
__device__ __forceinline__ float swz(float x) {
    return __int_as_float(__builtin_amdgcn_ds_swizzle(__float_as_int(x), PAT));
}

// ---- K0: convert W{q,k,v,o} -> bf16 packed; zero cnt ----
#define NW4 (4 * DIM * DIM / 4)     // 16384 float4 of W
#define NC4 ((NN + 3) / 4)          // 12500 int4 of cnt
__global__ __launch_bounds__(256) void convert_kernel(
    const float* __restrict__ Wq, const float* __restrict__ Wk,
    const float* __restrict__ Wv, const float* __restrict__ Wo,
    unsigned short* __restrict__ Wb, int* __restrict__ cnt)
{
    int i = blockIdx.x * 256 + threadIdx.x;
    if (i < NW4) {
        int mat = i >> 12;            // 4096 float4 per matrix
        int off = i & 4095;
        const float* Wsrc = (mat == 0) ? Wq : (mat == 1) ? Wk : (mat == 2) ? Wv : Wo;
        float4 f = ((const float4*)Wsrc)[off];
        uint2 o;
        o.x = (unsigned)f2b(f.x) | ((unsigned)f2b(f.y) << 16);
        o.y = (unsigned)f2b(f.z) | ((unsigned)f2b(f.w) << 16);
        ((uint2*)(Wb + (size_t)mat * DIM * DIM))[off] = o;
    } else if (i < NW4 + NC4) {
        ((int4*)cnt)[i - NW4] = make_int4(0, 0, 0, 0);
    }
}

// ---- K1: QKV via MFMA + folded RANK histogram. One matrix per block.
// HALF-W SPLIT STAGING (r15 post-mortem: counter-split was a no-op, qkv is
// latency-bound at 34% occ; its 34.8KB full-W LDS capped residency at
// 4 blocks/CU. Staging 64 rows at a time (17.4KB) doubles the cap to
// 8 blocks/CU = 32 waves = full wave-slot occupancy, while keeping the
// in-loop ds_read that r13 proved essential). LDS row index is ntl*16+m
// for BOTH halves (h*64 offset cancels). ----
__global__ __launch_bounds__(256) void qkv_mfma_kernel(
    const float* __restrict__ x, const unsigned short* __restrict__ Wb,
    const float* __restrict__ bq, const float* __restrict__ bk, const float* __restrict__ bv,
    unsigned short* __restrict__ qvb, unsigned short* __restrict__ kb,
    const int* __restrict__ tgt, int* __restrict__ cnt, int* __restrict__ rank)
{
    __shared__ unsigned short Wl[64 * LROW];    // 17408 B
    const int mat = blockIdx.x / TPB;           // 0=q, 1=k, 2=v
    const int tg  = blockIdx.x % TPB;
    const int tid = threadIdx.x;
    const int lane = tid & 63;
    const int warp = tid >> 6;
    const int m = lane & 15;
    const int quad = lane >> 4;

    // folded rank-histogram: grid-stride over edges; returned old count =
    // per-target rank (makes fill atomic-free)
    const int gsize = 3 * TPB * 256;
    for (int e = blockIdx.x * 256 + tid; e < NE; e += gsize)
        rank[e] = atomicAdd(cnt + tgt[e], 1);

    const unsigned short* Wg = Wb + (size_t)mat * DIM * DIM;
    const int rt = tg * 4 + warp;
    const bool act = (rt < NTILE);
    const int r0 = rt * 16;

    const float* bias_p = (mat == 0) ? bq : (mat == 1) ? bk : bv;

    v8s a[4];
    if (act) {
#pragma unroll
        for (int kt = 0; kt < 4; ++kt) {
            const float4* xr = (const float4*)(x + (size_t)(r0 + m) * DIM + kt * 32 + quad * 8);
            float4 f0 = xr[0], f1 = xr[1];
            v8s t;
            t[0] = (short)f2b(f0.x); t[1] = (short)f2b(f0.y);
            t[2] = (short)f2b(f0.z); t[3] = (short)f2b(f0.w);
            t[4] = (short)f2b(f1.x); t[5] = (short)f2b(f1.y);
            t[6] = (short)f2b(f1.z); t[7] = (short)f2b(f1.w);
            a[kt] = t;
        }
    }

    const int i0 = (lane & 1) ? 2 : 0;        // which two rows this lane stores

#pragma unroll
    for (int h = 0; h < 2; ++h) {
        if (h) __syncthreads();               // half-0 reads done before restage
        // stage W rows h*64 .. h*64+63
#pragma unroll
        for (int it = 0; it < 4; ++it) {
            int chunk = h * 1024 + it * 256 + tid;      // 16 uint4 per row
            int row = (chunk >> 4) - h * 64, c8 = chunk & 15;
            *(uint4*)(Wl + row * LROW + c8 * 8) = ((const uint4*)Wg)[chunk];
        }
        __syncthreads();

        if (act) {
#pragma unroll
            for (int ntl = 0; ntl < 4; ++ntl) {
                const int nt = h * 4 + ntl;
                v4f c = {0.f, 0.f, 0.f, 0.f};
#pragma unroll
                for (int kt = 0; kt < 4; ++kt) {
                    v8s b = *(const v8s*)(Wl + (ntl * 16 + m) * LROW + kt * 32 + quad * 8);
                    c = __builtin_amdgcn_mfma_f32_16x16x32_bf16(a[kt], b, c, 0, 0, 0);
                }
                int col = nt * 16 + m;           // C/D: col = lane&15
                float bias = bias_p[col];
                // pack (col, col^1) bf16 pair via partner-lane swizzle
                unsigned w0 = 0, w1 = 0;
#pragma unroll
                for (int i = 0; i < 4; ++i) {
                    unsigned own  = (unsigned)f2b(c[i] + bias);
                    unsigned part = (unsigned)__builtin_amdgcn_ds_swizzle((int)own, 0x041F) & 0xffffu;
                    unsigned w = (lane & 1) ? (part | (own << 16)) : (own | (part << 16));
                    if (i == i0)     w0 = w;
                    if (i == i0 + 1) w1 = w;
                }
                int colb = nt * 16 + (m & ~1);   // pair-base col (dword-aligned)
                int rowa = r0 + quad * 4 + i0;
                if (mat == 1) {
                    *(unsigned*)(kb + (size_t)rowa * DIM + colb)       = w0;
                    *(unsigned*)(kb + (size_t)(rowa + 1) * DIM + colb) = w1;
                } else {
                    int pos = colb * 2 + ((mat == 2) ? 2 : 0);   // interleaved qv
                    *(unsigned*)(qvb + (size_t)rowa * QVROW + pos)       = w0;
                    *(unsigned*)(qvb + (size_t)(rowa + 1) * QVROW + pos) = w1;
                }
            }
        }
    }
}

// ---- K2: per-block (256-elem) local exclusive scan + block sums ----
__global__ __launch_bounds__(256) void scan1_kernel(
    const int* __restrict__ cnt, int* __restrict__ off, int* __restrict__ bsum)
{
    __shared__ int ws4[4];
    const int tid = threadIdx.x, lane = tid & 63, wid = tid >> 6;
    int i = blockIdx.x * 256 + tid;
    int v0 = (i < NN) ? cnt[i] : 0;
    int incl = v0;
#pragma unroll
    for (int d = 1; d < 64; d <<= 1) {
        int t = __shfl_up(incl, d);
        if (lane >= d) incl += t;
    }
    if (lane == 63) ws4[wid] = incl;
    __syncthreads();
    int wexcl = 0;
#pragma unroll
    for (int t = 0; t < 3; ++t) if (t < wid) wexcl += ws4[t];
    if (i < NN) off[i] = wexcl + incl - v0;
    if (tid == 255) bsum[blockIdx.x] = wexcl + incl;
}

// ---- K3: each block scans all 196 block sums (redundantly), adds its own
// base to off; last block writes off[NN] = total. ----
__global__ __launch_bounds__(256) void scan23_kernel(
    const int* __restrict__ bsum, int* __restrict__ off)
{
    __shared__ int ws4[4];
    __shared__ int base_s, total_s;
    const int tid = threadIdx.x, lane = tid & 63, wid = tid >> 6;
    int v0 = (tid < SCAN_B) ? bsum[tid] : 0;
    int incl = v0;
#pragma unroll
    for (int d = 1; d < 64; d <<= 1) {
        int t = __shfl_up(incl, d);
        if (lane >= d) incl += t;
    }
    if (lane == 63) ws4[wid] = incl;
    __syncthreads();
    int wexcl = 0;
#pragma unroll
    for (int t = 0; t < 3; ++t) if (t < wid) wexcl += ws4[t];
    int excl = wexcl + incl - v0;
    if (tid == blockIdx.x) base_s = excl;
    if (tid == SCAN_B - 1) total_s = excl + v0;
    __syncthreads();
    int i = blockIdx.x * 256 + tid;
    if (i < NN) off[i] += base_s;
    if (blockIdx.x == SCAN_B - 1 && tid == 0) off[NN] = total_s;
}

// ---- K4: fill CSR, ATOMIC-FREE: pos = off[tgt] + rank. ----
__global__ __launch_bounds__(256) void fill_kernel(
    const int* __restrict__ tgt, const int* __restrict__ src,
    const int* __restrict__ off, const int* __restrict__ rank,
    int* __restrict__ edge_src)
{
    int e = blockIdx.x * 256 + threadIdx.x;
    if (e >= NE) return;
    int pos = off[tgt[e]] + rank[e];
    edge_src[pos] = src[e];
}

// ---- K5: fused attention (r11 version, at its gather-latency floor).
// 1 wave/node, interleaved-qv 8x8B gathers (MLP=8), SGPR gather
// addressing, swizzle xor-tree, VGPR 24. ----
__global__ __launch_bounds__(256) void attn_kernel(
    const int* __restrict__ off, const int* __restrict__ edge_src,
    const unsigned short* __restrict__ qvb, const unsigned short* __restrict__ kb,
    unsigned short* __restrict__ aggb)
{
    const int tid = threadIdx.x;
    const int lane = tid & 63;
    const int node = blockIdx.x * 4 + (tid >> 6);
    if (node >= NN) return;

    const int base = __builtin_amdgcn_readfirstlane(off[node]);
    const int deg  = __builtin_amdgcn_readfirstlane(off[node + 1]) - base;

    unsigned kw = *(const unsigned*)(kb + (size_t)node * DIM + 2 * lane);
    const float klo = blo(kw), khi = bhi(kw);
    const int j = lane & 7;             // position within 8-lane head group

    float ax = 0.f, ay = 0.f, ss = 0.f;

    uint2 qv[8];                        // literal-indexed only -> registers

    // one gather: uniform row base (SALU) + lane*8 offset
#define G1(BB, I) { \
        int si = __builtin_amdgcn_readlane(srcv, (BB) * 8 + (I)); \
        qv[I] = ((const uint2*)(qvb + ((size_t)(unsigned)si << 8)))[lane]; }

#define ACC1(I) { float pi = swz<((I) << 5) | 0x18>(p); \
        unsigned vv = qv[I].y; ax += pi * blo(vv); ay += pi * bhi(vv); }

    for (int c0 = 0; c0 < deg; c0 += 64) {
        const int nchunk = min(deg - c0, 64);                  // wave-uniform
        int srcv = edge_src[base + min(c0 + lane, deg - 1)];   // coalesced, all valid
        const int nbt = (nchunk + 7) >> 3;                     // 1..8 batches
        for (int bb = 0; bb < nbt; ++bb) {
            G1(bb, 0) G1(bb, 1) G1(bb, 2) G1(bb, 3)
            G1(bb, 4) G1(bb, 5) G1(bb, 6) G1(bb, 7)
            const int nbu = nchunk - bb * 8;                   // valid edges
            float part0 = blo(qv[0].x) * klo + bhi(qv[0].x) * khi;
            float part1 = blo(qv[1].x) * klo + bhi(qv[1].x) * khi;
            float part2 = blo(qv[2].x) * klo + bhi(qv[2].x) * khi;
            float part3 = blo(qv[3].x) * klo + bhi(qv[3].x) * khi;
            float part4 = blo(qv[4].x) * klo + bhi(qv[4].x) * khi;
            float part5 = blo(qv[5].x) * klo + bhi(qv[5].x) * khi;
            float part6 = blo(qv[6].x) * klo + bhi(qv[6].x) * khi;
            float part7 = blo(qv[7].x) * klo + bhi(qv[7].x) * khi;
            // xor-tree: stage 1 (xor 1), stage 2 (xor 2), stage 3 (xor 4)
            float r10 = ((j & 1) ? part1 : part0) + swz<0x041F>((j & 1) ? part0 : part1);
            float r11 = ((j & 1) ? part3 : part2) + swz<0x041F>((j & 1) ? part2 : part3);
            float r12 = ((j & 1) ? part5 : part4) + swz<0x041F>((j & 1) ? part4 : part5);
            float r13 = ((j & 1) ? part7 : part6) + swz<0x041F>((j & 1) ? part6 : part7);
            float r20 = ((j & 2) ? r11 : r10) + swz<0x081F>((j & 2) ? r10 : r11);
            float r21 = ((j & 2) ? r13 : r12) + swz<0x081F>((j & 2) ? r12 : r13);
            float tot = ((j & 4) ? r21 : r20) + swz<0x101F>((j & 4) ? r20 : r21);
            float p = (j < nbu) ? __expf(tot * 0.25f) : 0.f;   // 1/sqrt(HD); tail->0
            ss += p;                                           // own edge only
            ACC1(0) ACC1(1) ACC1(2) ACC1(3)
            ACC1(4) ACC1(5) ACC1(6) ACC1(7)
        }
    }
#undef G1
#undef ACC1

    // reduce ss across the 8-lane head group
    ss += swz<0x041F>(ss);
    ss += swz<0x081F>(ss);
    ss += swz<0x101F>(ss);

    unsigned* ap = (unsigned*)(aggb + (size_t)node * DIM + 2 * lane);
    if (deg == 0) {
        *ap = 0u;
    } else {
        float inv = 1.f / ss;
        *ap = (unsigned)f2b(ax * inv) | ((unsigned)f2b(ay * inv) << 16);
    }
}

// ---- K6: out = agg @ Wo.T + bo via MFMA, HALF-W SPLIT STAGING (same
// rationale as K1: 17.4KB LDS -> 8 blocks/CU), fp32 out ----
__global__ __launch_bounds__(256) void outproj_mfma_kernel(
    const unsigned short* __restrict__ aggb, const unsigned short* __restrict__ Wob,
    const float* __restrict__ bo, float* __restrict__ out)
{
    __shared__ unsigned short Wl[64 * LROW];    // 17408 B
    const int tid = threadIdx.x;
    const int lane = tid & 63;
    const int warp = tid >> 6;
    const int m = lane & 15;
    const int quad = lane >> 4;

    const int rt = blockIdx.x * 4 + warp;
    const bool act = (rt < NTILE);
    const int r0 = rt * 16;

    v8s a[4];
    if (act) {
#pragma unroll
        for (int kt = 0; kt < 4; ++kt)
            a[kt] = *(const v8s*)(aggb + (size_t)(r0 + m) * DIM + kt * 32 + quad * 8);
    }

#pragma unroll
    for (int h = 0; h < 2; ++h) {
        if (h) __syncthreads();
#pragma unroll
        for (int it = 0; it < 4; ++it) {
            int chunk = h * 1024 + it * 256 + tid;
            int row = (chunk >> 4) - h * 64, c8 = chunk & 15;
            *(uint4*)(Wl + row * LROW + c8 * 8) = ((const uint4*)Wob)[chunk];
        }
        __syncthreads();

        if (act) {
#pragma unroll
            for (int ntl = 0; ntl < 4; ++ntl) {
                const int nt = h * 4 + ntl;
                v4f c = {0.f, 0.f, 0.f, 0.f};
#pragma unroll
                for (int kt = 0; kt < 4; ++kt) {
                    v8s b = *(const v8s*)(Wl + (ntl * 16 + m) * LROW + kt * 32 + quad * 8);
                    c = __builtin_amdgcn_mfma_f32_16x16x32_bf16(a[kt], b, c, 0, 0, 0);
                }
                int col = nt * 16 + m;
                float bias = bo[col];
#pragma unroll
                for (int i = 0; i < 4; ++i) {
                    int row = r0 + quad * 4 + i;
                    out[(size_t)row * DIM + col] = c[i] + bias;
                }
            }
        }
    }
}

extern "C" void kernel_launch(void* const* d_in, const int* in_sizes, int n_in,
                              void* d_out, int out_size, void* d_ws, size_t ws_size,
                              hipStream_t stream) {
    const float* x  = (const float*)d_in[0];
    const int*   ei = (const int*)d_in[1];      // [2, NE]: row0 = tgt, row1 = src
    const float* Wq = (const float*)d_in[2];
    const float* bq = (const float*)d_in[3];
    const float* Wk = (const float*)d_in[4];
    const float* bk = (const float*)d_in[5];
    const float* Wv = (const float*)d_in[6];
    const float* bv = (const float*)d_in[7];
    const float* Wo = (const float*)d_in[8];
    const float* bo = (const float*)d_in[9];

    const int* tgt = ei;
    const int* src = ei + NE;

    char* ws = (char*)d_ws;
    const size_t SZ_QV = (size_t)NN * QVROW * 2;    // 25.6 MB interleaved q+v
    const size_t SZ_BF = (size_t)NN * DIM * 2;      // 12.8 MB

    unsigned short* qvb  = (unsigned short*)(ws);
    unsigned short* kb   = (unsigned short*)(ws + SZ_QV);
    unsigned short* aggb = (unsigned short*)(ws + SZ_QV + SZ_BF);
    unsigned short* Wb   = (unsigned short*)(ws + SZ_QV + 2 * SZ_BF);  // 4 mats, 128 KB

    char* wi = ws + SZ_QV + 2 * SZ_BF + (size_t)4 * DIM * DIM * 2;
    int* cnt      = (int*)(wi);
    int* off      = (int*)(wi + (size_t)NN * 4);
    int* rank     = (int*)(wi + (size_t)(2 * NN + 1) * 4);
    int* edge_src = (int*)(wi + (size_t)(2 * NN + 1 + NE) * 4);
    int* bsum     = (int*)(wi + (size_t)(2 * NN + 1 + 2 * NE) * 4);

    const int conv_blocks = (NW4 + NC4 + 255) / 256;
    const int edge_blocks = (NE + 255) / 256;  // 3125

    convert_kernel<<<conv_blocks, 256, 0, stream>>>(Wq, Wk, Wv, Wo, Wb, cnt);
    qkv_mfma_kernel<<<3 * TPB, 256, 0, stream>>>(x, Wb, bq, bk, bv, qvb, kb, tgt, cnt, rank);
    scan1_kernel<<<SCAN_B, 256, 0, stream>>>(cnt, off, bsum);
    scan23_kernel<<<SCAN_B, 256, 0, stream>>>(bsum, off);
    fill_kernel<<<edge_blocks, 256, 0, stream>>>(tgt, src, off, rank, edge_src);
    attn_kernel<<<(NN + 3) / 4, 256, 0, stream>>>(off, edge_src, qvb, kb, aggb);
    outproj_mfma_kernel<<<TPB, 256, 0, stream>>>(
        aggb, Wb + (size_t)3 * DIM * DIM, bo, (float*)d_out);
}

// Round 18
// 218.194 us; speedup vs baseline: 1.1526x; 1.0066x over previous
//
#include <hip/hip_runtime.h>
#include <math.h>

#define NN 50000
#define NE 800000
#define DIM 128
#define NH 8
#define HD 16
#define NTILE 3125            // NN/16 exactly
#define TPB 782               // ceil(NTILE/4) tile-groups per matrix
#define LROW 136              // LDS row stride in shorts (128 + 8 pad)
#define QVROW 256             // interleaved qv row: 256 shorts = 512 B
#define SCAN_B 196            // ceil(NN/256)

typedef short v8s __attribute__((ext_vector_type(8)));
typedef float v4f __attribute__((ext_vector_type(4)));

__device__ __forceinline__ unsigned short f2b(float f) {
    unsigned u = __float_as_uint(f);
    u = (u + 0x7fffu + ((u >> 16) & 1u)) >> 16;   // round-to-nearest-even
    return (unsigned short)u;
}
__device__ __forceinline__ float blo(unsigned w) { return __uint_as_float(w << 16); }
__device__ __forceinline__ float bhi(unsigned w) { return __uint_as_float(w & 0xffff0000u); }

// immediate-pattern lane swizzle (BitMode): src = ((lane & and) | or) ^ xor, per 32-half
template<int PAT>
__device__ __forceinline__ float swz(float x) {
    return __int_as_float(__builtin_amdgcn_ds_swizzle(__float_as_int(x), PAT));
}

// ---- K0: convert W{q,k,v,o} -> bf16 packed; zero cnt ----
#define NW4 (4 * DIM * DIM / 4)     // 16384 float4 of W
#define NC4 ((NN + 3) / 4)          // 12500 int4 of cnt
__global__ __launch_bounds__(256) void convert_kernel(
    const float* __restrict__ Wq, const float* __restrict__ Wk,
    const float* __restrict__ Wv, const float* __restrict__ Wo,
    unsigned short* __restrict__ Wb, int* __restrict__ cnt)
{
    int i = blockIdx.x * 256 + threadIdx.x;
    if (i < NW4) {
        int mat = i >> 12;            // 4096 float4 per matrix
        int off = i & 4095;
        const float* Wsrc = (mat == 0) ? Wq : (mat == 1) ? Wk : (mat == 2) ? Wv : Wo;
        float4 f = ((const float4*)Wsrc)[off];
        uint2 o;
        o.x = (unsigned)f2b(f.x) | ((unsigned)f2b(f.y) << 16);
        o.y = (unsigned)f2b(f.z) | ((unsigned)f2b(f.w) << 16);
        ((uint2*)(Wb + (size_t)mat * DIM * DIM))[off] = o;
    } else if (i < NW4 + NC4) {
        ((int4*)cnt)[i - NW4] = make_int4(0, 0, 0, 0);
    }
}

// ---- K1: QKV via MFMA + folded RANK histogram. One matrix per block.
// FULL-W LDS staging = the r12 measured optimum (56.5us). r17 proved the
// half-W occupancy boost HURTS here: qkv's floor is the device-serialized
// atomic stream (r11: 55.4us standalone; r15: line-split null), so extra
// resident blocks buy nothing while doubled barriers lengthen the serial
// path. The atomicAdd return value = edge's rank (fill is atomic-free). ----
__global__ __launch_bounds__(256) void qkv_mfma_kernel(
    const float* __restrict__ x, const unsigned short* __restrict__ Wb,
    const float* __restrict__ bq, const float* __restrict__ bk, const float* __restrict__ bv,
    unsigned short* __restrict__ qvb, unsigned short* __restrict__ kb,
    const int* __restrict__ tgt, int* __restrict__ cnt, int* __restrict__ rank)
{
    __shared__ unsigned short Wl[DIM * LROW];   // 34816 B
    const int mat = blockIdx.x / TPB;           // 0=q, 1=k, 2=v
    const int tg  = blockIdx.x % TPB;
    const int tid = threadIdx.x;
    const int lane = tid & 63;
    const int warp = tid >> 6;
    const int m = lane & 15;
    const int quad = lane >> 4;

    // folded rank-histogram: grid-stride over edges; returned old count =
    // per-target rank (coalesced 4B write)
    const int gsize = 3 * TPB * 256;
    for (int e = blockIdx.x * 256 + tid; e < NE; e += gsize)
        rank[e] = atomicAdd(cnt + tgt[e], 1);

    const unsigned short* Wg = Wb + (size_t)mat * DIM * DIM;
#pragma unroll
    for (int it = 0; it < 8; ++it) {
        int chunk = it * 256 + tid;           // 0..2047
        int row = chunk >> 4, c8 = chunk & 15;
        *(uint4*)(Wl + row * LROW + c8 * 8) = ((const uint4*)Wg)[chunk];
    }
    __syncthreads();

    const int rt = tg * 4 + warp;
    if (rt >= NTILE) return;
    const int r0 = rt * 16;

    const float* bias_p = (mat == 0) ? bq : (mat == 1) ? bk : bv;

    v8s a[4];
#pragma unroll
    for (int kt = 0; kt < 4; ++kt) {
        const float4* xr = (const float4*)(x + (size_t)(r0 + m) * DIM + kt * 32 + quad * 8);
        float4 f0 = xr[0], f1 = xr[1];
        v8s t;
        t[0] = (short)f2b(f0.x); t[1] = (short)f2b(f0.y);
        t[2] = (short)f2b(f0.z); t[3] = (short)f2b(f0.w);
        t[4] = (short)f2b(f1.x); t[5] = (short)f2b(f1.y);
        t[6] = (short)f2b(f1.z); t[7] = (short)f2b(f1.w);
        a[kt] = t;
    }

    const int i0 = (lane & 1) ? 2 : 0;        // which two rows this lane stores

#pragma unroll
    for (int nt = 0; nt < 8; ++nt) {
        v4f c = {0.f, 0.f, 0.f, 0.f};
#pragma unroll
        for (int kt = 0; kt < 4; ++kt) {
            v8s b = *(const v8s*)(Wl + (nt * 16 + m) * LROW + kt * 32 + quad * 8);
            c = __builtin_amdgcn_mfma_f32_16x16x32_bf16(a[kt], b, c, 0, 0, 0);
        }
        int col = nt * 16 + m;           // C/D: col = lane&15
        float bias = bias_p[col];
        // pack (col, col^1) bf16 pair via partner-lane swizzle; keep the two
        // rows this lane is responsible for (even: i=0,1; odd: i=2,3)
        unsigned w0 = 0, w1 = 0;
#pragma unroll
        for (int i = 0; i < 4; ++i) {
            unsigned own  = (unsigned)f2b(c[i] + bias);
            unsigned part = (unsigned)__builtin_amdgcn_ds_swizzle((int)own, 0x041F) & 0xffffu;
            unsigned w = (lane & 1) ? (part | (own << 16)) : (own | (part << 16));
            if (i == i0)     w0 = w;
            if (i == i0 + 1) w1 = w;
        }
        int colb = nt * 16 + (m & ~1);   // pair-base col (dword-aligned)
        int rowa = r0 + quad * 4 + i0;
        if (mat == 1) {
            *(unsigned*)(kb + (size_t)rowa * DIM + colb)       = w0;
            *(unsigned*)(kb + (size_t)(rowa + 1) * DIM + colb) = w1;
        } else {
            int pos = colb * 2 + ((mat == 2) ? 2 : 0);   // interleaved qv layout
            *(unsigned*)(qvb + (size_t)rowa * QVROW + pos)       = w0;
            *(unsigned*)(qvb + (size_t)(rowa + 1) * QVROW + pos) = w1;
        }
    }
}

// ---- K2: per-block (256-elem) local exclusive scan + block sums ----
__global__ __launch_bounds__(256) void scan1_kernel(
    const int* __restrict__ cnt, int* __restrict__ off, int* __restrict__ bsum)
{
    __shared__ int ws4[4];
    const int tid = threadIdx.x, lane = tid & 63, wid = tid >> 6;
    int i = blockIdx.x * 256 + tid;
    int v0 = (i < NN) ? cnt[i] : 0;
    int incl = v0;
#pragma unroll
    for (int d = 1; d < 64; d <<= 1) {
        int t = __shfl_up(incl, d);
        if (lane >= d) incl += t;
    }
    if (lane == 63) ws4[wid] = incl;
    __syncthreads();
    int wexcl = 0;
#pragma unroll
    for (int t = 0; t < 3; ++t) if (t < wid) wexcl += ws4[t];
    if (i < NN) off[i] = wexcl + incl - v0;
    if (tid == 255) bsum[blockIdx.x] = wexcl + incl;
}

// ---- K3: each block scans all 196 block sums (redundantly), adds its own
// base to off; last block writes off[NN] = total. ----
__global__ __launch_bounds__(256) void scan23_kernel(
    const int* __restrict__ bsum, int* __restrict__ off)
{
    __shared__ int ws4[4];
    __shared__ int base_s, total_s;
    const int tid = threadIdx.x, lane = tid & 63, wid = tid >> 6;
    int v0 = (tid < SCAN_B) ? bsum[tid] : 0;
    int incl = v0;
#pragma unroll
    for (int d = 1; d < 64; d <<= 1) {
        int t = __shfl_up(incl, d);
        if (lane >= d) incl += t;
    }
    if (lane == 63) ws4[wid] = incl;
    __syncthreads();
    int wexcl = 0;
#pragma unroll
    for (int t = 0; t < 3; ++t) if (t < wid) wexcl += ws4[t];
    int excl = wexcl + incl - v0;
    if (tid == blockIdx.x) base_s = excl;
    if (tid == SCAN_B - 1) total_s = excl + v0;
    __syncthreads();
    int i = blockIdx.x * 256 + tid;
    if (i < NN) off[i] += base_s;
    if (blockIdx.x == SCAN_B - 1 && tid == 0) off[NN] = total_s;
}

// ---- K4: fill CSR, ATOMIC-FREE: pos = off[tgt] + rank. ----
__global__ __launch_bounds__(256) void fill_kernel(
    const int* __restrict__ tgt, const int* __restrict__ src,
    const int* __restrict__ off, const int* __restrict__ rank,
    int* __restrict__ edge_src)
{
    int e = blockIdx.x * 256 + threadIdx.x;
    if (e >= NE) return;
    int pos = off[tgt[e]] + rank[e];
    edge_src[pos] = src[e];
}

// ---- K5: fused attention (r11 version, at its gather-latency floor).
// 1 wave/node, interleaved-qv 8x8B gathers (MLP=8), SGPR gather
// addressing, swizzle xor-tree, VGPR 24. ----
__global__ __launch_bounds__(256) void attn_kernel(
    const int* __restrict__ off, const int* __restrict__ edge_src,
    const unsigned short* __restrict__ qvb, const unsigned short* __restrict__ kb,
    unsigned short* __restrict__ aggb)
{
    const int tid = threadIdx.x;
    const int lane = tid & 63;
    const int node = blockIdx.x * 4 + (tid >> 6);
    if (node >= NN) return;

    const int base = __builtin_amdgcn_readfirstlane(off[node]);
    const int deg  = __builtin_amdgcn_readfirstlane(off[node + 1]) - base;

    unsigned kw = *(const unsigned*)(kb + (size_t)node * DIM + 2 * lane);
    const float klo = blo(kw), khi = bhi(kw);
    const int j = lane & 7;             // position within 8-lane head group

    float ax = 0.f, ay = 0.f, ss = 0.f;

    uint2 qv[8];                        // literal-indexed only -> registers

    // one gather: uniform row base (SALU) + lane*8 offset
#define G1(BB, I) { \
        int si = __builtin_amdgcn_readlane(srcv, (BB) * 8 + (I)); \
        qv[I] = ((const uint2*)(qvb + ((size_t)(unsigned)si << 8)))[lane]; }

#define ACC1(I) { float pi = swz<((I) << 5) | 0x18>(p); \
        unsigned vv = qv[I].y; ax += pi * blo(vv); ay += pi * bhi(vv); }

    for (int c0 = 0; c0 < deg; c0 += 64) {
        const int nchunk = min(deg - c0, 64);                  // wave-uniform
        int srcv = edge_src[base + min(c0 + lane, deg - 1)];   // coalesced, all valid
        const int nbt = (nchunk + 7) >> 3;                     // 1..8 batches
        for (int bb = 0; bb < nbt; ++bb) {
            G1(bb, 0) G1(bb, 1) G1(bb, 2) G1(bb, 3)
            G1(bb, 4) G1(bb, 5) G1(bb, 6) G1(bb, 7)
            const int nbu = nchunk - bb * 8;                   // valid edges
            float part0 = blo(qv[0].x) * klo + bhi(qv[0].x) * khi;
            float part1 = blo(qv[1].x) * klo + bhi(qv[1].x) * khi;
            float part2 = blo(qv[2].x) * klo + bhi(qv[2].x) * khi;
            float part3 = blo(qv[3].x) * klo + bhi(qv[3].x) * khi;
            float part4 = blo(qv[4].x) * klo + bhi(qv[4].x) * khi;
            float part5 = blo(qv[5].x) * klo + bhi(qv[5].x) * khi;
            float part6 = blo(qv[6].x) * klo + bhi(qv[6].x) * khi;
            float part7 = blo(qv[7].x) * klo + bhi(qv[7].x) * khi;
            // xor-tree: stage 1 (xor 1), stage 2 (xor 2), stage 3 (xor 4)
            float r10 = ((j & 1) ? part1 : part0) + swz<0x041F>((j & 1) ? part0 : part1);
            float r11 = ((j & 1) ? part3 : part2) + swz<0x041F>((j & 1) ? part2 : part3);
            float r12 = ((j & 1) ? part5 : part4) + swz<0x041F>((j & 1) ? part4 : part5);
            float r13 = ((j & 1) ? part7 : part6) + swz<0x041F>((j & 1) ? part6 : part7);
            float r20 = ((j & 2) ? r11 : r10) + swz<0x081F>((j & 2) ? r10 : r11);
            float r21 = ((j & 2) ? r13 : r12) + swz<0x081F>((j & 2) ? r12 : r13);
            float tot = ((j & 4) ? r21 : r20) + swz<0x101F>((j & 4) ? r20 : r21);
            float p = (j < nbu) ? __expf(tot * 0.25f) : 0.f;   // 1/sqrt(HD); tail->0
            ss += p;                                           // own edge only
            ACC1(0) ACC1(1) ACC1(2) ACC1(3)
            ACC1(4) ACC1(5) ACC1(6) ACC1(7)
        }
    }
#undef G1
#undef ACC1

    // reduce ss across the 8-lane head group
    ss += swz<0x041F>(ss);
    ss += swz<0x081F>(ss);
    ss += swz<0x101F>(ss);

    unsigned* ap = (unsigned*)(aggb + (size_t)node * DIM + 2 * lane);
    if (deg == 0) {
        *ap = 0u;
    } else {
        float inv = 1.f / ss;
        *ap = (unsigned)f2b(ax * inv) | ((unsigned)f2b(ay * inv) << 16);
    }
}

// ---- K6: out = agg @ Wo.T + bo via MFMA, HALF-W SPLIT STAGING (kept from
// r17: no atomic stream here, so the 17.4KB-LDS 8-blocks/CU occupancy boost
// is pure win -- r17's flat total despite qkv +14us implies outproj -14us). ----
__global__ __launch_bounds__(256) void outproj_mfma_kernel(
    const unsigned short* __restrict__ aggb, const unsigned short* __restrict__ Wob,
    const float* __restrict__ bo, float* __restrict__ out)
{
    __shared__ unsigned short Wl[64 * LROW];    // 17408 B
    const int tid = threadIdx.x;
    const int lane = tid & 63;
    const int warp = tid >> 6;
    const int m = lane & 15;
    const int quad = lane >> 4;

    const int rt = blockIdx.x * 4 + warp;
    const bool act = (rt < NTILE);
    const int r0 = rt * 16;

    v8s a[4];
    if (act) {
#pragma unroll
        for (int kt = 0; kt < 4; ++kt)
            a[kt] = *(const v8s*)(aggb + (size_t)(r0 + m) * DIM + kt * 32 + quad * 8);
    }

#pragma unroll
    for (int h = 0; h < 2; ++h) {
        if (h) __syncthreads();
#pragma unroll
        for (int it = 0; it < 4; ++it) {
            int chunk = h * 1024 + it * 256 + tid;
            int row = (chunk >> 4) - h * 64, c8 = chunk & 15;
            *(uint4*)(Wl + row * LROW + c8 * 8) = ((const uint4*)Wob)[chunk];
        }
        __syncthreads();

        if (act) {
#pragma unroll
            for (int ntl = 0; ntl < 4; ++ntl) {
                const int nt = h * 4 + ntl;
                v4f c = {0.f, 0.f, 0.f, 0.f};
#pragma unroll
                for (int kt = 0; kt < 4; ++kt) {
                    v8s b = *(const v8s*)(Wl + (ntl * 16 + m) * LROW + kt * 32 + quad * 8);
                    c = __builtin_amdgcn_mfma_f32_16x16x32_bf16(a[kt], b, c, 0, 0, 0);
                }
                int col = nt * 16 + m;
                float bias = bo[col];
#pragma unroll
                for (int i = 0; i < 4; ++i) {
                    int row = r0 + quad * 4 + i;
                    out[(size_t)row * DIM + col] = c[i] + bias;
                }
            }
        }
    }
}

extern "C" void kernel_launch(void* const* d_in, const int* in_sizes, int n_in,
                              void* d_out, int out_size, void* d_ws, size_t ws_size,
                              hipStream_t stream) {
    const float* x  = (const float*)d_in[0];
    const int*   ei = (const int*)d_in[1];      // [2, NE]: row0 = tgt, row1 = src
    const float* Wq = (const float*)d_in[2];
    const float* bq = (const float*)d_in[3];
    const float* Wk = (const float*)d_in[4];
    const float* bk = (const float*)d_in[5];
    const float* Wv = (const float*)d_in[6];
    const float* bv = (const float*)d_in[7];
    const float* Wo = (const float*)d_in[8];
    const float* bo = (const float*)d_in[9];

    const int* tgt = ei;
    const int* src = ei + NE;

    char* ws = (char*)d_ws;
    const size_t SZ_QV = (size_t)NN * QVROW * 2;    // 25.6 MB interleaved q+v
    const size_t SZ_BF = (size_t)NN * DIM * 2;      // 12.8 MB

    unsigned short* qvb  = (unsigned short*)(ws);
    unsigned short* kb   = (unsigned short*)(ws + SZ_QV);
    unsigned short* aggb = (unsigned short*)(ws + SZ_QV + SZ_BF);
    unsigned short* Wb   = (unsigned short*)(ws + SZ_QV + 2 * SZ_BF);  // 4 mats, 128 KB

    char* wi = ws + SZ_QV + 2 * SZ_BF + (size_t)4 * DIM * DIM * 2;
    int* cnt      = (int*)(wi);
    int* off      = (int*)(wi + (size_t)NN * 4);
    int* rank     = (int*)(wi + (size_t)(2 * NN + 1) * 4);
    int* edge_src = (int*)(wi + (size_t)(2 * NN + 1 + NE) * 4);
    int* bsum     = (int*)(wi + (size_t)(2 * NN + 1 + 2 * NE) * 4);

    const int conv_blocks = (NW4 + NC4 + 255) / 256;
    const int edge_blocks = (NE + 255) / 256;  // 3125

    convert_kernel<<<conv_blocks, 256, 0, stream>>>(Wq, Wk, Wv, Wo, Wb, cnt);
    qkv_mfma_kernel<<<3 * TPB, 256, 0, stream>>>(x, Wb, bq, bk, bv, qvb, kb, tgt, cnt, rank);
    scan1_kernel<<<SCAN_B, 256, 0, stream>>>(cnt, off, bsum);
    scan23_kernel<<<SCAN_B, 256, 0, stream>>>(bsum, off);
    fill_kernel<<<edge_blocks, 256, 0, stream>>>(tgt, src, off, rank, edge_src);
    attn_kernel<<<(NN + 3) / 4, 256, 0, stream>>>(off, edge_src, qvb, kb, aggb);
    outproj_mfma_kernel<<<TPB, 256, 0, stream>>>(
        aggb, Wb + (size_t)3 * DIM * DIM, bo, (float*)d_out);
}